// Round 12
// baseline (152.018 us; speedup 1.0000x reference)
//
#include <hip/hip_runtime.h>

#define LN 1024
#define FF 128
#define HH 128
#define CC 10
#define DD 34314
#define OFF_W0 0
#define OFF_B0 16384
#define OFF_W1 16512
#define OFF_B1 32896
#define OFF_W2 33024
#define OFF_B2 34304
#define TILE 1024     // floats per stream per tile
#define NT 16         // tiles per 16384-float W region

__global__ void init_delta(float* delta) { *delta = 0.f; }

__device__ __forceinline__ float invmut(const float* h, int node, int par) {
    return 1.f / fmaxf(fabsf(h[node] - h[par]), 1e-7f);
}

// One block = one level-8 subtree (4 leaves), 1024 threads, 256 blocks.
// 15 row-streams staged tile-by-tile into LDS via global_load_lds (width=4,
// always 4-aligned), double-buffered: DMA of tile t+1 overlaps consume of t.
// In-flight bytes no longer VGPR-limited (m97 pattern). Consume: 15 stride-1
// ds_read_b32 (conflict-free) + fused delta + distributive matvec.
__global__ __launch_bounds__(1024, 1)
__attribute__((amdgpu_waves_per_eu(4, 4)))
void fused_kernel(const float* __restrict__ W,
                  const float* __restrict__ x,
                  const float* __restrict__ heights,
                  float* __restrict__ out,
                  float* __restrict__ delta_out) {
    const int bid  = blockIdx.x;
    const int m    = ((bid & 7) << 5) | (bid >> 3);   // XCD-chunked bijection (256 = 8*32)
    const int tid  = threadIdx.x;
    const int lane = tid & 63;
    const int wv   = tid >> 6;          // 0..15

    int path[9];
    {
        int n = 255 + m;
#pragma unroll
        for (int k = 0; k < 9; ++k) { path[k] = n; n = (n - 1) >> 1; }
    }
    const float* R[15];
#pragma unroll
    for (int k = 0; k < 9; ++k) R[k] = W + (size_t)path[k] * DD;
    const int n9a = 511 + 2 * m, n9b = n9a + 1;
    R[9]  = W + (size_t)n9a * DD;
    R[10] = W + (size_t)n9b * DD;
#pragma unroll
    for (int q = 0; q < 4; ++q) R[11 + q] = W + (size_t)(1023 + 4 * m + q) * DD;

    float wgt[15];
#pragma unroll
    for (int k = 0; k < 8; ++k)
        wgt[k] = ((m & ((1 << k) - 1)) == 0) ? invmut(heights, path[k], path[k + 1]) : 0.f;
    wgt[8]  = 0.f;                       // root: sum-of-squares handled via sacc
    wgt[9]  = invmut(heights, n9a, path[0]);
    wgt[10] = invmut(heights, n9b, path[0]);
#pragma unroll
    for (int q = 0; q < 4; ++q)
        wgt[11 + q] = invmut(heights, 1023 + 4 * m + q, (q < 2) ? n9a : n9b);
    const float sqmask = (m == 0) ? 1.f : 0.f;

    __shared__ float buf[2][15][TILE];   // 120 KB staging double-buffer
    __shared__ float ins[4][HH];
    __shared__ float lgts[4][CC];
    __shared__ float red[16];

    if (tid < 512) { const int q = tid >> 7, t = tid & 127; ins[q][t] = x[(4 * m + q) * FF + t]; }
    if (tid < 4 * CC) ((float*)lgts)[tid] = 0.f;

    float dacc = 0.f, sacc = 0.f;

    const int fg  = tid >> 7;            // 0..7 : f-group
    const int col = tid & 127;           // fixed output column per thread

    // ---------------- layers 0 and 1 (128 -> 128), DMA-staged ----------------
#pragma unroll 1
    for (int layer = 0; layer < 2; ++layer) {
        const int offW = layer ? OFF_W1 : OFF_W0;
        const int offB = layer ? OFF_B1 : OFF_B0;

        float yacc[4] = {0.f, 0.f, 0.f, 0.f};

        // stage tile 0 into buf[0]: 240 issues, 15 per wave
#pragma unroll
        for (int j = 0; j < 15; ++j) {
            const int id = wv * 15 + j, r = id >> 4, c = id & 15;
            const float* gsrc = R[r] + offW + 0 * TILE + c * 64 + lane;
            __builtin_amdgcn_global_load_lds(
                (const __attribute__((address_space(1))) void*)gsrc,
                (__attribute__((address_space(3))) void*)&buf[0][r][c * 64], 4, 0, 0);
        }

#pragma unroll 1
        for (int t = 0; t < NT; ++t) {
            const int cur = t & 1;
            __syncthreads();             // vmcnt drain: buf[cur] staged; prior reads of buf[cur^1] done
            if (t + 1 < NT) {
#pragma unroll
                for (int j = 0; j < 15; ++j) {
                    const int id = wv * 15 + j, r = id >> 4, c = id & 15;
                    const float* gsrc = R[r] + offW + (t + 1) * TILE + c * 64 + lane;
                    __builtin_amdgcn_global_load_lds(
                        (const __attribute__((address_space(1))) void*)gsrc,
                        (__attribute__((address_space(3))) void*)&buf[cur ^ 1][r][c * 64], 4, 0, 0);
                }
            }
            // consume tile t from buf[cur]
            const int f = t * 8 + fg;
            float w[15];
#pragma unroll
            for (int r = 0; r < 15; ++r) w[r] = buf[cur][r][tid];
            float e = 0.f;
#pragma unroll
            for (int k = 0; k < 9; ++k) { e += w[k]; dacc += fabsf(w[k]) * wgt[k]; }
            sacc += w[8] * w[8];
            dacc += fabsf(w[9]) * wgt[9] + fabsf(w[10]) * wgt[10];
            const float xv0 = ins[0][f], xv1 = ins[1][f], xv2 = ins[2][f], xv3 = ins[3][f];
            dacc += fabsf(w[11]) * wgt[11] + fabsf(w[12]) * wgt[12]
                  + fabsf(w[13]) * wgt[13] + fabsf(w[14]) * wgt[14];
            yacc[0] += xv0 * (e + w[9]  + w[11]);
            yacc[1] += xv1 * (e + w[9]  + w[12]);
            yacc[2] += xv2 * (e + w[10] + w[13]);
            yacc[3] += xv3 * (e + w[10] + w[14]);
        }
        __syncthreads();                 // all consumes done; buf free for scratch

        // reduce yacc across the 8 f-groups via scratch in buf[0] (16 KB)
        float* scratch = &buf[0][0][0];
#pragma unroll
        for (int q = 0; q < 4; ++q) scratch[q * 1024 + tid] = yacc[q];
        __syncthreads();
        if (tid < 512) {
            const int q = tid >> 7, c2 = tid & 127;   // q uniform per wave
            float eb = 0.f;
#pragma unroll
            for (int k = 0; k < 9; ++k) {
                const float v = R[k][offB + c2];
                eb += v;
                if (q == 0) { dacc += fabsf(v) * wgt[k]; if (k == 8) sacc += v * v; }
            }
            const float a0 = R[9][offB + c2];
            const float a1 = R[10][offB + c2];
            if (q == 0) dacc += fabsf(a0) * wgt[9];
            if (q == 2) dacc += fabsf(a1) * wgt[10];
            const float bq = R[11 + q][offB + c2];
            dacc += fabsf(bq) * wgt[11 + q];
            float s = eb + ((q < 2) ? a0 : a1) + bq;
#pragma unroll
            for (int g = 0; g < 8; ++g) s += scratch[q * 1024 + g * 128 + c2];
            ins[q][c2] = fmaxf(s, 0.f);
        }
        __syncthreads();                 // h visible; scratch reads done before next stage
    }

    // ---------------- layer 2 (128 -> 10), float2 direct (3.7% of traffic) ----------------
    {
        const float2* S2[15];
#pragma unroll
        for (int r = 0; r < 15; ++r) S2[r] = reinterpret_cast<const float2*>(R[r] + OFF_W2);
        if (tid < 640) {                 // 640 float2 = 1280 weights per row
            const int h  = tid / 5;
            const int c0 = (tid - 5 * h) * 2;
            float ex = 0.f, ey = 0.f;
#pragma unroll
            for (int k = 0; k < 9; ++k) {
                const float2 w = S2[k][tid];
                ex += w.x; ey += w.y;
                dacc += (fabsf(w.x) + fabsf(w.y)) * wgt[k];
                if (k == 8) sacc += w.x * w.x + w.y * w.y;
            }
            const float2 wa0 = S2[9][tid];
            const float2 wa1 = S2[10][tid];
            dacc += (fabsf(wa0.x) + fabsf(wa0.y)) * wgt[9];
            dacc += (fabsf(wa1.x) + fabsf(wa1.y)) * wgt[10];
#pragma unroll
            for (int q = 0; q < 4; ++q) {
                const float2 wb = S2[11 + q][tid];
                dacc += (fabsf(wb.x) + fabsf(wb.y)) * wgt[11 + q];
                const float2 wa = (q < 2) ? wa0 : wa1;
                const float hv = ins[q][h];
                atomicAdd(&lgts[q][c0],     hv * (ex + wa.x + wb.x));
                atomicAdd(&lgts[q][c0 + 1], hv * (ey + wa.y + wb.y));
            }
        }
        __syncthreads();
        if (tid < CC) {
            float eb = 0.f;
#pragma unroll
            for (int k = 0; k < 9; ++k) {
                const float v = R[k][OFF_B2 + tid];
                eb += v;
                dacc += fabsf(v) * wgt[k];
                if (k == 8) sacc += v * v;
            }
            const float a0 = R[9][OFF_B2 + tid];
            const float a1 = R[10][OFF_B2 + tid];
            dacc += fabsf(a0) * wgt[9] + fabsf(a1) * wgt[10];
#pragma unroll
            for (int q = 0; q < 4; ++q) {
                const float bq = R[11 + q][OFF_B2 + tid];
                dacc += fabsf(bq) * wgt[11 + q];
                lgts[q][tid] += eb + ((q < 2) ? a0 : a1) + bq;
            }
        }
        __syncthreads();
    }

    // ---------------- softmax (one thread per leaf) ----------------
    if (tid < 4) {
        const int q = tid;
        float mx = lgts[q][0];
#pragma unroll
        for (int c = 1; c < CC; ++c) mx = fmaxf(mx, lgts[q][c]);
        float e[CC], s = 0.f;
#pragma unroll
        for (int c = 0; c < CC; ++c) { e[c] = expf(lgts[q][c] - mx); s += e[c]; }
        const float inv = 1.f / s;
#pragma unroll
        for (int c = 0; c < CC; ++c) out[(4 * m + q) * CC + c] = e[c] * inv;
    }

    // ---------------- delta reduce ----------------
    float v = dacc + sacc * sqmask;
    for (int o = 32; o > 0; o >>= 1) v += __shfl_down(v, o);
    if (lane == 0) red[wv] = v;
    __syncthreads();
    if (tid == 0) {
        float s = 0.f;
#pragma unroll
        for (int w = 0; w < 16; ++w) s += red[w];
        atomicAdd(delta_out, s);
    }
}

extern "C" void kernel_launch(void* const* d_in, const int* in_sizes, int n_in,
                              void* d_out, int out_size, void* d_ws, size_t ws_size,
                              hipStream_t stream) {
    const float* x       = (const float*)d_in[0];   // (1024, 128)
    const float* W       = (const float*)d_in[1];   // (2047, 34314)
    const float* heights = (const float*)d_in[2];   // (2047,)

    float* out   = (float*)d_out;
    float* delta = (float*)d_out + LN * CC;

    init_delta<<<1, 1, 0, stream>>>(delta);
    fused_kernel<<<256, 1024, 0, stream>>>(W, x, heights, out, delta);
}